// Round 3
// baseline (189.078 us; speedup 1.0000x reference)
//
#include <hip/hip_runtime.h>

// QuantumLayer: AmplitudeEmbedding(normalize) + per-wire RX(w_i) + <Z_i>.
// Closed form: out[b][i] = cos(w_i) * (1 - 2 * S_i / SS)
//   SS  = sum_k x[b][k]^2            (after NaN->0 scrub)
//   S_i = sum_{k : bit_(3-i)(k)==1} x[b][k]^2
// Derivation: U = (X)RX(w_i); U^T Z_i U = cos(w_i) Z_i + sin(w_i) Y_i, and
// <Y_i> = 0 on the real embedded state. Pure memory-bound streaming op:
// 128 MiB read + 32 MiB write -> ~25-30 us roofline @ 6.3 TB/s.

constexpr int BLOCK = 256;
constexpr int MAX_BLOCKS = 2048;   // 256 CU x 8 blocks/CU (G11: grid-stride the rest)

// clang native vector type: __builtin_nontemporal_load rejects HIP's float4
// (a HIP_vector_type class) but accepts ext_vector_type.
typedef float fvec4 __attribute__((ext_vector_type(4)));

__global__ __launch_bounds__(BLOCK) void quantum_z_kernel(
    const float* __restrict__ x,
    const float* __restrict__ w,
    float* __restrict__ out,
    int n_vec4)                      // total float4 elements = BATCH*4
{
    // cos(w[j]) for this lane's output component; L1-broadcast load, 4 values
    const int j0 = threadIdx.x & 3;
    const float cw = cosf(w[j0]);

    const int stride = gridDim.x * BLOCK;
    for (int gid = blockIdx.x * BLOCK + threadIdx.x; gid < n_vec4; gid += stride) {
        int j = gid & 3;             // which quarter of the 16-amp sample

        // streaming read: nontemporal (no reuse, don't pollute L2/LLC)
        const fvec4* xp = reinterpret_cast<const fvec4*>(x) + gid;
        fvec4 v = __builtin_nontemporal_load(xp);

        // NaN scrub (matches reference semantics; no-op on real data)
        float a = (v.x != v.x) ? 0.0f : v.x;
        float b = (v.y != v.y) ? 0.0f : v.y;
        float c = (v.z != v.z) ? 0.0f : v.z;
        float d = (v.w != v.w) ? 0.0f : v.w;

        float p0 = a * a, p1 = b * b, p2 = c * c, p3 = d * d;
        float q  = (p0 + p1) + (p2 + p3);  // this lane's partial sum-of-squares
        float t2 = p2 + p3;                // bit1-set elements within the quarter
        float t3 = p1 + p3;                // bit0-set elements within the quarter

        // 4-lane butterfly (lanes j=0..3 of this sample), 7 shuffles total.
        // element k = j*4 + jj: bit3=j>>1, bit2=j&1, bit1=jj>>1, bit0=jj&1
        float r1   = __shfl_xor(q, 1);
        float pair = q + r1;                       // sum of this lane-pair
        float oddq = (j & 1) ? q : r1;             // q of the odd lane in pair
        float r2   = __shfl_xor(pair, 2);
        float SS   = pair + r2;                    // full sum of squares
        float S0   = (j & 2) ? pair : r2;          // q2+q3  (wire 0, bit3)
        float S1   = oddq + __shfl_xor(oddq, 2);   // q1+q3  (wire 1, bit2)
        float S2   = t2 + __shfl_xor(t2, 1);       // wire 2 (bit1)
        S2 += __shfl_xor(S2, 2);
        float S3   = t3 + __shfl_xor(t3, 1);       // wire 3 (bit0)
        S3 += __shfl_xor(S3, 2);

        // lane j emits output component j (coalesced dword store)
        float Sj = (j & 2) ? ((j & 1) ? S3 : S2) : ((j & 1) ? S1 : S0);
        float z  = cw * (1.0f - 2.0f * Sj / SS);
        __builtin_nontemporal_store(z, out + gid);
    }
}

extern "C" void kernel_launch(void* const* d_in, const int* in_sizes, int n_in,
                              void* d_out, int out_size, void* d_ws, size_t ws_size,
                              hipStream_t stream) {
    const float* x = (const float*)d_in[0];   // [BATCH, 16] f32
    const float* w = (const float*)d_in[1];   // [4] f32
    float* out = (float*)d_out;               // [BATCH, 4] f32

    int n_vec4 = in_sizes[0] / 4;             // BATCH*4 work items, one float4 each
    int grid = (n_vec4 + BLOCK - 1) / BLOCK;
    if (grid > MAX_BLOCKS) grid = MAX_BLOCKS;
    hipLaunchKernelGGL(quantum_z_kernel, dim3(grid), dim3(BLOCK), 0, stream,
                       x, w, out, n_vec4);
}